// Round 1
// baseline (1283.634 us; speedup 1.0000x reference)
//
#include <hip/hip_runtime.h>
#include <math.h>

#define BB 2
#define TT 2048
#define CC 1024
#define HH 16
#define DD 64
#define WINW 256

constexpr int MROWS = BB * TT;        // 4096
constexpr int NQKV  = 3 * CC;         // 3072
constexpr int QKV_LD = 3 * CC;        // qkv row stride (floats)

// ---------------------------------------------------------------------------
// Tiled fp32 GEMM:  Cc[m,n] = sum_k A[m,k] * Bw[n,k]  (+ bias[n])
// A: (M,K) row-major.  Bw: (N,K) row-major (i.e. we compute A @ Bw^T).
// 64x64 tile, BK=16, 256 threads, 4x4 accum per thread.
// ---------------------------------------------------------------------------
template <bool BIAS>
__global__ __launch_bounds__(256)
void gemm_nt_f32(const float* __restrict__ A, const float* __restrict__ Bw,
                 const float* __restrict__ bias, float* __restrict__ Cc,
                 int M, int N, int K) {
    __shared__ float As[64][17];
    __shared__ float Bs[64][17];

    const int tid = threadIdx.x;
    const int tx = tid & 15;       // 0..15 -> output col group
    const int ty = tid >> 4;       // 0..15 -> output row group
    const int bn = blockIdx.x * 64;
    const int bm = blockIdx.y * 64;

    const int ldrow = tid >> 2;          // 0..63
    const int ldcol = (tid & 3) * 4;     // 0,4,8,12

    float acc[4][4] = {};

    for (int k0 = 0; k0 < K; k0 += 16) {
        float4 av = *(const float4*)&A [(size_t)(bm + ldrow) * K + k0 + ldcol];
        float4 bv = *(const float4*)&Bw[(size_t)(bn + ldrow) * K + k0 + ldcol];
        As[ldrow][ldcol + 0] = av.x; As[ldrow][ldcol + 1] = av.y;
        As[ldrow][ldcol + 2] = av.z; As[ldrow][ldcol + 3] = av.w;
        Bs[ldrow][ldcol + 0] = bv.x; Bs[ldrow][ldcol + 1] = bv.y;
        Bs[ldrow][ldcol + 2] = bv.z; Bs[ldrow][ldcol + 3] = bv.w;
        __syncthreads();

#pragma unroll
        for (int kk = 0; kk < 16; ++kk) {
            float a[4], b[4];
#pragma unroll
            for (int i = 0; i < 4; ++i) a[i] = As[ty * 4 + i][kk];
#pragma unroll
            for (int j = 0; j < 4; ++j) b[j] = Bs[tx * 4 + j][kk];
#pragma unroll
            for (int i = 0; i < 4; ++i)
#pragma unroll
                for (int j = 0; j < 4; ++j)
                    acc[i][j] = fmaf(a[i], b[j], acc[i][j]);
        }
        __syncthreads();
    }

#pragma unroll
    for (int i = 0; i < 4; ++i) {
        float4 o;
        o.x = acc[i][0]; o.y = acc[i][1]; o.z = acc[i][2]; o.w = acc[i][3];
        if (BIAS) {
            o.x += bias[bn + tx * 4 + 0];
            o.y += bias[bn + tx * 4 + 1];
            o.z += bias[bn + tx * 4 + 2];
            o.w += bias[bn + tx * 4 + 3];
        }
        *(float4*)&Cc[(size_t)(bm + ty * 4 + i) * N + bn + tx * 4] = o;
    }
}

// ---------------------------------------------------------------------------
// RoPE in place on q,k parts of qkv. One thread per (b,t,h,pair i), rotates
// both the q pair and the k pair. theta_i = 10000^(-i/32), ang = t * theta_i.
// ---------------------------------------------------------------------------
__global__ __launch_bounds__(256)
void rope_kernel(float* __restrict__ qkv) {
    int idx = blockIdx.x * 256 + threadIdx.x;     // over B*T*H*32
    int i = idx & 31;
    int h = (idx >> 5) & (HH - 1);
    int t = (idx >> 9) & (TT - 1);
    int b = idx >> 20;                            // 2*2048*16*32 = 2^21 total

    float theta = powf(10000.0f, -(float)i / 32.0f);
    float ang = (float)t * theta;
    float s, c;
    sincosf(ang, &s, &c);

    float* row = qkv + (size_t)(b * TT + t) * QKV_LD + h * (3 * DD);
    float q1 = row[2 * i], q2 = row[2 * i + 1];
    row[2 * i]     = q1 * c - q2 * s;
    row[2 * i + 1] = q1 * s + q2 * c;
    float k1 = row[DD + 2 * i], k2 = row[DD + 2 * i + 1];
    row[DD + 2 * i]     = k1 * c - k2 * s;
    row[DD + 2 * i + 1] = k1 * s + k2 * c;
}

// ---------------------------------------------------------------------------
// Windowed causal attention. One wave per query (b,h,i); 4 waves per block.
// Keys j in [max(0, i-WIN), i]  (<= 257 keys).
// ---------------------------------------------------------------------------
__global__ __launch_bounds__(256)
void attn_kernel(const float* __restrict__ qkv, float* __restrict__ out) {
    __shared__ float sh_q[4][64];
    __shared__ float sh_p[4][WINW + 8];   // up to 257 probs per wave

    const int wave = threadIdx.x >> 6;
    const int lane = threadIdx.x & 63;
    const int wid = blockIdx.x * 4 + wave;     // 0 .. B*H*T-1
    const int i = wid & (TT - 1);
    const int h = (wid >> 11) & (HH - 1);
    const int b = wid >> 15;

    const float* head = qkv + (size_t)(b * TT) * QKV_LD + h * (3 * DD);
    const int jstart = (i > WINW) ? (i - WINW) : 0;
    const int nk = i - jstart + 1;             // 1..257

    // stage q for this wave
    sh_q[wave][lane] = head[(size_t)i * QKV_LD + lane];
    __syncthreads();

    // scores: keys-per-lane, 5 fixed iterations
    float sarr[5];
    float m = -INFINITY;
#pragma unroll
    for (int it = 0; it < 5; ++it) {
        int jj = it * 64 + lane;
        float s = -INFINITY;
        if (jj < nk) {
            const float* krow = head + (size_t)(jstart + jj) * QKV_LD + DD;
            float acc = 0.0f;
#pragma unroll
            for (int d4 = 0; d4 < 16; ++d4) {
                float4 qv = *(const float4*)&sh_q[wave][d4 * 4];
                float4 kv = *(const float4*)&krow[d4 * 4];
                acc += qv.x * kv.x + qv.y * kv.y + qv.z * kv.z + qv.w * kv.w;
            }
            s = acc * 0.125f;
            m = fmaxf(m, s);
        }
        sarr[it] = s;
    }
    // wave max
#pragma unroll
    for (int off = 32; off > 0; off >>= 1)
        m = fmaxf(m, __shfl_xor(m, off));

    // exp + wave sum; stash p into LDS
    float lsum = 0.0f;
#pragma unroll
    for (int it = 0; it < 5; ++it) {
        int jj = it * 64 + lane;
        if (jj < nk) {
            float p = expf(sarr[it] - m);
            lsum += p;
            sh_p[wave][jj] = p;
        }
    }
    float sum = lsum;
#pragma unroll
    for (int off = 32; off > 0; off >>= 1)
        sum += __shfl_xor(sum, off);
    __syncthreads();

    // PV: lane owns output dim d = lane
    const float* vbase = head + 2 * DD + lane;
    float acc = 0.0f;
    for (int jj = 0; jj < nk; ++jj)
        acc += sh_p[wave][jj] * vbase[(size_t)(jstart + jj) * QKV_LD];

    out[(size_t)(b * TT + i) * CC + h * DD + lane] = acc / sum;
}

// ---------------------------------------------------------------------------
extern "C" void kernel_launch(void* const* d_in, const int* in_sizes, int n_in,
                              void* d_out, int out_size, void* d_ws, size_t ws_size,
                              hipStream_t stream) {
    const float* x     = (const float*)d_in[0];
    const float* w_qkv = (const float*)d_in[1];
    const float* w_out = (const float*)d_in[2];
    const float* b_out = (const float*)d_in[3];
    float* out = (float*)d_out;

    float* qkv  = (float*)d_ws;                        // 4096*3072 f32 = 50.3 MB
    float* attn = qkv + (size_t)MROWS * NQKV;          // 4096*1024 f32 = 16.8 MB

    // 1) qkv = x @ w_qkv^T
    gemm_nt_f32<false><<<dim3(NQKV / 64, MROWS / 64), 256, 0, stream>>>(
        x, w_qkv, nullptr, qkv, MROWS, NQKV, CC);

    // 2) RoPE on q,k in place
    rope_kernel<<<(BB * TT * HH * 32) / 256, 256, 0, stream>>>(qkv);

    // 3) windowed attention -> attn (already laid out (b,t,h*D+d))
    attn_kernel<<<(BB * HH * TT) / 4, 256, 0, stream>>>(qkv, attn);

    // 4) out = attn @ w_out^T + b_out
    gemm_nt_f32<true><<<dim3(CC / 64, MROWS / 64), 256, 0, stream>>>(
        attn, w_out, b_out, out, MROWS, CC, CC);
}

// Round 2
// 473.681 us; speedup vs baseline: 2.7099x; 2.7099x over previous
//
#include <hip/hip_runtime.h>
#include <math.h>

#define BB 2
#define TT 2048
#define CC 1024
#define HH 16
#define DD 64
#define WINW 256

constexpr int MROWS  = BB * TT;    // 4096
constexpr int NQKV   = 3 * CC;     // 3072
constexpr int QKV_LD = 3 * CC;     // qkv row stride (elems)

typedef unsigned short ushort_t;
typedef __attribute__((ext_vector_type(8))) short  bf16x8;
typedef __attribute__((ext_vector_type(4))) float  f32x4;
typedef __attribute__((ext_vector_type(8))) unsigned short u16x8;

__device__ __forceinline__ float bf2f(ushort_t u) {
    return __uint_as_float(((unsigned int)u) << 16);
}
__device__ __forceinline__ ushort_t f2bf(float f) {
    unsigned int u = __float_as_uint(f);
    u += 0x7fffu + ((u >> 16) & 1u);      // RNE
    return (ushort_t)(u >> 16);
}

__device__ __forceinline__ void async16(void* lds, const void* g) {
    __builtin_amdgcn_global_load_lds(
        (const __attribute__((address_space(1))) unsigned int*)g,
        (__attribute__((address_space(3))) unsigned int*)lds, 16, 0, 0);
}

// ---------------------------------------------------------------------------
// f32 -> bf16 conversion, 4 elems/thread
// ---------------------------------------------------------------------------
__global__ __launch_bounds__(256)
void f32_to_bf16(const float* __restrict__ in, ushort_t* __restrict__ out) {
    int i = (blockIdx.x * 256 + threadIdx.x) * 4;
    float4 v = *(const float4*)&in[i];
    ushort4 o;
    o.x = f2bf(v.x); o.y = f2bf(v.y); o.z = f2bf(v.z); o.w = f2bf(v.w);
    *(ushort4*)&out[i] = o;
}

// ---------------------------------------------------------------------------
// bf16 MFMA GEMM (m97 structure): C[m,n] = sum_k A[m,k] * Bw[n,k]  (+bias)
// A:(M,K) bf16 row-major, Bw:(N,K) bf16 row-major. 128x128 tile, BK=32,
// 256 threads (4 waves, 2x2), mfma_f32_16x16x32_bf16, global_load_lds x16.
// ---------------------------------------------------------------------------
template <bool BIAS, bool OUT_BF16>
__global__ __launch_bounds__(256)
void gemm_nt_mfma(const ushort_t* __restrict__ A, const ushort_t* __restrict__ Bw,
                  const float* __restrict__ bias, void* __restrict__ Cc,
                  int M, int N, int K) {
    __shared__ __align__(16) ushort_t As[128 * 32];   // 8 KB
    __shared__ __align__(16) ushort_t Bs[128 * 32];   // 8 KB

    const int tid  = threadIdx.x;
    const int lane = tid & 63;
    const int wv   = tid >> 6;            // 0..3
    const int wr   = wv >> 1;             // wave row (0..1) -> 64 rows
    const int wc   = wv & 1;              // wave col (0..1) -> 64 cols
    const int bm   = blockIdx.y * 128;
    const int bn   = blockIdx.x * 128;

    const int srow = tid >> 2;            // 0..63
    const int scol = (tid & 3) * 8;       // 0,8,16,24

    const ushort_t* Ag = A + (size_t)(bm + srow) * K + scol;
    const ushort_t* Bg = Bw + (size_t)(bn + srow) * K + scol;

    f32x4 acc[4][4];
#pragma unroll
    for (int m = 0; m < 4; ++m)
#pragma unroll
        for (int n = 0; n < 4; ++n)
            acc[m][n] = f32x4{0.f, 0.f, 0.f, 0.f};

    const int fr = lane & 15;             // fragment row/col within 16
    const int fq = lane >> 4;             // 0..3 -> k-chunk

    for (int k0 = 0; k0 < K; k0 += 32) {
        // stage A,B tiles (rows 0-63 then 64-127), 16B per lane
        async16(&As[tid * 8],        Ag);
        async16(&As[2048 + tid * 8], Ag + (size_t)64 * K);
        async16(&Bs[tid * 8],        Bg);
        async16(&Bs[2048 + tid * 8], Bg + (size_t)64 * K);
        Ag += 32; Bg += 32;
        __syncthreads();   // compiler emits vmcnt(0) drain before s_barrier

        bf16x8 af[4], bfv[4];
#pragma unroll
        for (int m = 0; m < 4; ++m)
            af[m] = *(const bf16x8*)&As[(wr * 64 + m * 16 + fr) * 32 + fq * 8];
#pragma unroll
        for (int n = 0; n < 4; ++n)
            bfv[n] = *(const bf16x8*)&Bs[(wc * 64 + n * 16 + fr) * 32 + fq * 8];
#pragma unroll
        for (int m = 0; m < 4; ++m)
#pragma unroll
            for (int n = 0; n < 4; ++n)
                acc[m][n] = __builtin_amdgcn_mfma_f32_16x16x32_bf16(
                    af[m], bfv[n], acc[m][n], 0, 0, 0);
        __syncthreads();
    }

    // epilogue: C/D layout col=lane&15, row=(lane>>4)*4+j  [m89-verified]
#pragma unroll
    for (int m = 0; m < 4; ++m) {
#pragma unroll
        for (int n = 0; n < 4; ++n) {
            const int col = bn + wc * 64 + n * 16 + fr;
            const float bv = BIAS ? bias[col] : 0.0f;
#pragma unroll
            for (int j = 0; j < 4; ++j) {
                const int row = bm + wr * 64 + m * 16 + fq * 4 + j;
                float v = acc[m][n][j] + bv;
                if (OUT_BF16)
                    ((ushort_t*)Cc)[(size_t)row * N + col] = f2bf(v);
                else
                    ((float*)Cc)[(size_t)row * N + col] = v;
            }
        }
    }
}

// ---------------------------------------------------------------------------
// RoPE in place on bf16 qkv. One thread per (b,t,h,pair i); rotates q and k.
// theta_i = 10000^(-i/32), ang = t * theta_i.
// ---------------------------------------------------------------------------
__global__ __launch_bounds__(256)
void rope_kernel(ushort_t* __restrict__ qkv) {
    int idx = blockIdx.x * 256 + threadIdx.x;     // over B*T*H*32 = 2^21
    int i = idx & 31;
    int h = (idx >> 5) & (HH - 1);
    int t = (idx >> 9) & (TT - 1);
    int b = idx >> 20;

    float theta = powf(10000.0f, -(float)i / 32.0f);
    float ang = (float)t * theta;
    float s, c;
    sincosf(ang, &s, &c);

    ushort_t* row = qkv + (size_t)(b * TT + t) * QKV_LD + h * (3 * DD);
    float q1 = bf2f(row[2 * i]), q2 = bf2f(row[2 * i + 1]);
    row[2 * i]     = f2bf(q1 * c - q2 * s);
    row[2 * i + 1] = f2bf(q1 * s + q2 * c);
    float k1 = bf2f(row[DD + 2 * i]), k2 = bf2f(row[DD + 2 * i + 1]);
    row[DD + 2 * i]     = f2bf(k1 * c - k2 * s);
    row[DD + 2 * i + 1] = f2bf(k1 * s + k2 * c);
}

// ---------------------------------------------------------------------------
// Windowed causal attention on bf16 qkv, fp32 math, bf16 output.
// One wave per query (b,h,i); 4 waves per block.
// ---------------------------------------------------------------------------
__global__ __launch_bounds__(256)
void attn_kernel(const ushort_t* __restrict__ qkv, ushort_t* __restrict__ out) {
    __shared__ float sh_q[4][64];
    __shared__ float sh_p[4][WINW + 8];

    const int wave = threadIdx.x >> 6;
    const int lane = threadIdx.x & 63;
    const int wid = blockIdx.x * 4 + wave;     // 0 .. B*H*T-1
    const int i = wid & (TT - 1);
    const int h = (wid >> 11) & (HH - 1);
    const int b = wid >> 15;

    const ushort_t* head = qkv + (size_t)(b * TT) * QKV_LD + h * (3 * DD);
    const int jstart = (i > WINW) ? (i - WINW) : 0;
    const int nk = i - jstart + 1;             // 1..257

    sh_q[wave][lane] = bf2f(head[(size_t)i * QKV_LD + lane]);
    __syncthreads();

    // scores, keys-per-lane
    float sarr[5];
    float m = -INFINITY;
#pragma unroll
    for (int it = 0; it < 5; ++it) {
        int jj = it * 64 + lane;
        float s = -INFINITY;
        if (jj < nk) {
            const u16x8* krow = (const u16x8*)(head + (size_t)(jstart + jj) * QKV_LD + DD);
            float acc = 0.0f;
#pragma unroll
            for (int c = 0; c < 8; ++c) {
                u16x8 kv = krow[c];
#pragma unroll
                for (int e = 0; e < 8; ++e)
                    acc = fmaf(sh_q[wave][c * 8 + e], bf2f(kv[e]), acc);
            }
            s = acc * 0.125f;
            m = fmaxf(m, s);
        }
        sarr[it] = s;
    }
#pragma unroll
    for (int off = 32; off > 0; off >>= 1)
        m = fmaxf(m, __shfl_xor(m, off));

    float lsum = 0.0f;
#pragma unroll
    for (int it = 0; it < 5; ++it) {
        int jj = it * 64 + lane;
        if (jj < nk) {
            float p = expf(sarr[it] - m);
            lsum += p;
            sh_p[wave][jj] = p;
        }
    }
    float sum = lsum;
#pragma unroll
    for (int off = 32; off > 0; off >>= 1)
        sum += __shfl_xor(sum, off);
    __syncthreads();

    // PV: lane owns dim d=lane; 4 independent chains
    const ushort_t* vcol = head + 2 * DD + lane;
    float a0 = 0.f, a1 = 0.f, a2 = 0.f, a3 = 0.f;
    int jj = 0;
    for (; jj + 4 <= nk; jj += 4) {
        a0 = fmaf(sh_p[wave][jj + 0], bf2f(vcol[(size_t)(jstart + jj + 0) * QKV_LD]), a0);
        a1 = fmaf(sh_p[wave][jj + 1], bf2f(vcol[(size_t)(jstart + jj + 1) * QKV_LD]), a1);
        a2 = fmaf(sh_p[wave][jj + 2], bf2f(vcol[(size_t)(jstart + jj + 2) * QKV_LD]), a2);
        a3 = fmaf(sh_p[wave][jj + 3], bf2f(vcol[(size_t)(jstart + jj + 3) * QKV_LD]), a3);
    }
    for (; jj < nk; ++jj)
        a0 = fmaf(sh_p[wave][jj], bf2f(vcol[(size_t)(jstart + jj) * QKV_LD]), a0);
    float acc = (a0 + a1) + (a2 + a3);

    out[(size_t)(b * TT + i) * CC + h * DD + lane] = f2bf(acc / sum);
}

// ---------------------------------------------------------------------------
extern "C" void kernel_launch(void* const* d_in, const int* in_sizes, int n_in,
                              void* d_out, int out_size, void* d_ws, size_t ws_size,
                              hipStream_t stream) {
    const float* x     = (const float*)d_in[0];
    const float* w_qkv = (const float*)d_in[1];
    const float* w_out = (const float*)d_in[2];
    const float* b_out = (const float*)d_in[3];
    float* out = (float*)d_out;

    ushort_t* qkv_b  = (ushort_t*)d_ws;                         // 12.58M elems, 25.2 MB
    ushort_t* attn_b = qkv_b  + (size_t)MROWS * NQKV;           //  4.19M, 8.4 MB
    ushort_t* xb     = attn_b + (size_t)MROWS * CC;             //  4.19M, 8.4 MB
    ushort_t* wqb    = xb     + (size_t)MROWS * CC;             //  3.15M, 6.3 MB
    ushort_t* wob    = wqb    + (size_t)NQKV * CC;              //  1.05M, 2.1 MB

    // 0) convert inputs to bf16
    f32_to_bf16<<<(MROWS * CC) / 1024, 256, 0, stream>>>(x, xb);
    f32_to_bf16<<<(NQKV * CC) / 1024, 256, 0, stream>>>(w_qkv, wqb);
    f32_to_bf16<<<(CC * CC) / 1024, 256, 0, stream>>>(w_out, wob);

    // 1) qkv = x @ w_qkv^T   (bf16 out)
    gemm_nt_mfma<false, true><<<dim3(NQKV / 128, MROWS / 128), 256, 0, stream>>>(
        xb, wqb, nullptr, qkv_b, MROWS, NQKV, CC);

    // 2) RoPE on q,k in place (bf16)
    rope_kernel<<<(BB * TT * HH * 32) / 256, 256, 0, stream>>>(qkv_b);

    // 3) windowed attention -> attn_b (bf16, layout (b,t,h*D+d))
    attn_kernel<<<(BB * HH * TT) / 4, 256, 0, stream>>>(qkv_b, attn_b);

    // 4) out = attn @ w_out^T + b_out  (fp32 out)
    gemm_nt_mfma<true, false><<<dim3(CC / 128, MROWS / 128), 256, 0, stream>>>(
        attn_b, wob, b_out, out, MROWS, CC, CC);
}

// Round 3
// 122.261 us; speedup vs baseline: 10.4991x; 3.8743x over previous
//
#include <hip/hip_runtime.h>
#include <math.h>

#define BB 2
#define TT 2048
#define CC 1024
#define HH 16
#define DD 64
#define WINW 256

constexpr int MROWS  = BB * TT;    // 4096
constexpr int NQKV   = 3 * CC;     // 3072
constexpr int QKV_LD = 3 * CC;     // qkv row stride (elems)

typedef unsigned short ushort_t;
typedef __attribute__((ext_vector_type(8))) short  bf16x8;
typedef __attribute__((ext_vector_type(4))) float  f32x4;
typedef __attribute__((ext_vector_type(8))) unsigned short u16x8;

__device__ __forceinline__ float bf2f(ushort_t u) {
    return __uint_as_float(((unsigned int)u) << 16);
}
__device__ __forceinline__ ushort_t f2bf(float f) {
    unsigned int u = __float_as_uint(f);
    u += 0x7fffu + ((u >> 16) & 1u);      // RNE
    return (ushort_t)(u >> 16);
}

__device__ __forceinline__ void async16(void* lds, const void* g) {
    __builtin_amdgcn_global_load_lds(
        (const __attribute__((address_space(1))) unsigned int*)g,
        (__attribute__((address_space(3))) unsigned int*)lds, 16, 0, 0);
}

// ---------------------------------------------------------------------------
// f32 -> bf16 conversion, 4 elems/thread
// ---------------------------------------------------------------------------
__global__ __launch_bounds__(256)
void f32_to_bf16(const float* __restrict__ in, ushort_t* __restrict__ out) {
    int i = (blockIdx.x * 256 + threadIdx.x) * 4;
    float4 v = *(const float4*)&in[i];
    ushort4 o;
    o.x = f2bf(v.x); o.y = f2bf(v.y); o.z = f2bf(v.z); o.w = f2bf(v.w);
    *(ushort4*)&out[i] = o;
}

// ---------------------------------------------------------------------------
// bf16 MFMA GEMM (m97 structure): C[m,n] = sum_k A[m,k] * Bw[n,k]  (+bias)
// 128x128 tile, BK=32, 4 waves, mfma_f32_16x16x32_bf16, global_load_lds x16.
// ---------------------------------------------------------------------------
template <bool BIAS, bool OUT_BF16>
__global__ __launch_bounds__(256)
void gemm_nt_mfma(const ushort_t* __restrict__ A, const ushort_t* __restrict__ Bw,
                  const float* __restrict__ bias, void* __restrict__ Cc,
                  int M, int N, int K) {
    __shared__ __align__(16) ushort_t As[128 * 32];   // 8 KB
    __shared__ __align__(16) ushort_t Bs[128 * 32];   // 8 KB

    const int tid  = threadIdx.x;
    const int lane = tid & 63;
    const int wv   = tid >> 6;
    const int wr   = wv >> 1;
    const int wc   = wv & 1;
    const int bm   = blockIdx.y * 128;
    const int bn   = blockIdx.x * 128;

    const int srow = tid >> 2;
    const int scol = (tid & 3) * 8;

    const ushort_t* Ag = A + (size_t)(bm + srow) * K + scol;
    const ushort_t* Bg = Bw + (size_t)(bn + srow) * K + scol;

    f32x4 acc[4][4];
#pragma unroll
    for (int m = 0; m < 4; ++m)
#pragma unroll
        for (int n = 0; n < 4; ++n)
            acc[m][n] = f32x4{0.f, 0.f, 0.f, 0.f};

    const int fr = lane & 15;
    const int fq = lane >> 4;

    for (int k0 = 0; k0 < K; k0 += 32) {
        async16(&As[tid * 8],        Ag);
        async16(&As[2048 + tid * 8], Ag + (size_t)64 * K);
        async16(&Bs[tid * 8],        Bg);
        async16(&Bs[2048 + tid * 8], Bg + (size_t)64 * K);
        Ag += 32; Bg += 32;
        __syncthreads();

        bf16x8 af[4], bfv[4];
#pragma unroll
        for (int m = 0; m < 4; ++m)
            af[m] = *(const bf16x8*)&As[(wr * 64 + m * 16 + fr) * 32 + fq * 8];
#pragma unroll
        for (int n = 0; n < 4; ++n)
            bfv[n] = *(const bf16x8*)&Bs[(wc * 64 + n * 16 + fr) * 32 + fq * 8];
#pragma unroll
        for (int m = 0; m < 4; ++m)
#pragma unroll
            for (int n = 0; n < 4; ++n)
                acc[m][n] = __builtin_amdgcn_mfma_f32_16x16x32_bf16(
                    af[m], bfv[n], acc[m][n], 0, 0, 0);
        __syncthreads();
    }

#pragma unroll
    for (int m = 0; m < 4; ++m) {
#pragma unroll
        for (int n = 0; n < 4; ++n) {
            const int col = bn + wc * 64 + n * 16 + fr;
            const float bv = BIAS ? bias[col] : 0.0f;
#pragma unroll
            for (int j = 0; j < 4; ++j) {
                const int row = bm + wr * 64 + m * 16 + fq * 4 + j;
                float v = acc[m][n][j] + bv;
                if (OUT_BF16)
                    ((ushort_t*)Cc)[(size_t)row * N + col] = f2bf(v);
                else
                    ((float*)Cc)[(size_t)row * N + col] = v;
            }
        }
    }
}

// ---------------------------------------------------------------------------
// RoPE in place on bf16 qkv.
// ---------------------------------------------------------------------------
__global__ __launch_bounds__(256)
void rope_kernel(ushort_t* __restrict__ qkv) {
    int idx = blockIdx.x * 256 + threadIdx.x;
    int i = idx & 31;
    int h = (idx >> 5) & (HH - 1);
    int t = (idx >> 9) & (TT - 1);
    int b = idx >> 20;

    float theta = powf(10000.0f, -(float)i / 32.0f);
    float ang = (float)t * theta;
    float s, c;
    sincosf(ang, &s, &c);

    ushort_t* row = qkv + (size_t)(b * TT + t) * QKV_LD + h * (3 * DD);
    float q1 = bf2f(row[2 * i]), q2 = bf2f(row[2 * i + 1]);
    row[2 * i]     = f2bf(q1 * c - q2 * s);
    row[2 * i + 1] = f2bf(q1 * s + q2 * c);
    float k1 = bf2f(row[DD + 2 * i]), k2 = bf2f(row[DD + 2 * i + 1]);
    row[DD + 2 * i]     = f2bf(k1 * c - k2 * s);
    row[DD + 2 * i + 1] = f2bf(k1 * s + k2 * c);
}

// ---------------------------------------------------------------------------
// MFMA windowed flash attention.
// Block = (b, h, 64-query tile), 4 waves x 16 queries.
// K-window tiles of 64 keys staged in LDS (K padded-72; V transposed to Vt).
// Per wave: QK^T via mfma 16x16x32 -> mask -> online softmax -> P via LDS
// bounce -> PV via mfma. fp32 state, bf16 operands.
// ---------------------------------------------------------------------------
#define MASKNEG (-1e30f)

__global__ __launch_bounds__(256)
void attn_mfma(const ushort_t* __restrict__ qkv, ushort_t* __restrict__ out) {
    __shared__ __align__(16) ushort_t Ks[64 * 72];       // K[key][kdim], pad 72
    __shared__ __align__(16) ushort_t Vt[64 * 72];       // Vt[d][key],  pad 72
    __shared__ __align__(16) ushort_t Ps[4][16 * 72];    // per-wave P[q][key]

    const int tid  = threadIdx.x;
    const int lane = tid & 63;
    const int wv   = tid >> 6;
    const int fr   = lane & 15;
    const int fq   = lane >> 4;

    const int blk = blockIdx.x;        // (b*16 + h)*32 + qt
    const int qt  = blk & 31;
    const int h   = (blk >> 5) & 15;
    const int b   = blk >> 9;
    const int q0  = qt * 64;

    const ushort_t* base = qkv + (size_t)(b * TT) * QKV_LD + h * (3 * DD);

    // Q fragments: wave's rows q0 + wv*16 + fr
    bf16x8 qf0, qf1;
    {
        const ushort_t* qrow = base + (size_t)(q0 + wv * 16 + fr) * QKV_LD;
        qf0 = *(const bf16x8*)(qrow + fq * 8);
        qf1 = *(const bf16x8*)(qrow + 32 + fq * 8);
    }

    f32x4 oacc[4];
#pragma unroll
    for (int nd = 0; nd < 4; ++nd) oacc[nd] = f32x4{0.f, 0.f, 0.f, 0.f};
    float mj[4], lj[4];
#pragma unroll
    for (int j = 0; j < 4; ++j) { mj[j] = MASKNEG; lj[j] = 0.f; }

    // staging indices: row r = tid>>2, col chunk c = (tid&3)*16
    const int sr = tid >> 2;
    const int sc = (tid & 3) * 16;

    const int kstart = (q0 >= WINW) ? (q0 - WINW) : 0;

    for (int kt0 = kstart; kt0 < q0 + 64; kt0 += 64) {
        __syncthreads();   // previous tile's LDS reads complete
        // ---- stage K tile ----
        {
            const ushort_t* krow = base + (size_t)(kt0 + sr) * QKV_LD + DD + sc;
            u16x8 a = *(const u16x8*)krow;
            u16x8 bvv = *(const u16x8*)(krow + 8);
            *(u16x8*)&Ks[sr * 72 + sc]     = a;
            *(u16x8*)&Ks[sr * 72 + sc + 8] = bvv;
        }
        // ---- stage V tile transposed ----
        {
            const ushort_t* vrow = base + (size_t)(kt0 + sr) * QKV_LD + 2 * DD + sc;
            u16x8 a = *(const u16x8*)vrow;
            u16x8 bvv = *(const u16x8*)(vrow + 8);
#pragma unroll
            for (int e = 0; e < 8; ++e) {
                Vt[(sc + e) * 72 + sr]     = a[e];
                Vt[(sc + 8 + e) * 72 + sr] = bvv[e];
            }
        }
        __syncthreads();

        // ---- QK^T: 4 col-chunks x 2 k-chunks ----
        f32x4 s[4];
#pragma unroll
        for (int n = 0; n < 4; ++n) {
            bf16x8 kb0 = *(const bf16x8*)&Ks[(n * 16 + fr) * 72 + fq * 8];
            bf16x8 kb1 = *(const bf16x8*)&Ks[(n * 16 + fr) * 72 + 32 + fq * 8];
            f32x4 z = f32x4{0.f, 0.f, 0.f, 0.f};
            z = __builtin_amdgcn_mfma_f32_16x16x32_bf16(qf0, kb0, z, 0, 0, 0);
            s[n] = __builtin_amdgcn_mfma_f32_16x16x32_bf16(qf1, kb1, z, 0, 0, 0);
        }

        // ---- mask + scale; per-row tile max ----
        float pmax[4];
#pragma unroll
        for (int j = 0; j < 4; ++j) pmax[j] = MASKNEG;
#pragma unroll
        for (int n = 0; n < 4; ++n) {
            const int key = kt0 + n * 16 + fr;
#pragma unroll
            for (int j = 0; j < 4; ++j) {
                const int qi = q0 + wv * 16 + fq * 4 + j;
                const bool ok = (key <= qi) && (key >= qi - WINW);
                float sv = ok ? s[n][j] * 0.125f : MASKNEG;
                s[n][j] = sv;
                pmax[j] = fmaxf(pmax[j], sv);
            }
        }
        // reduce max across the 16-lane row group
#pragma unroll
        for (int off = 1; off < 16; off <<= 1)
#pragma unroll
            for (int j = 0; j < 4; ++j)
                pmax[j] = fmaxf(pmax[j], __shfl_xor(pmax[j], off));

        // ---- online softmax update + write P ----
        float tl[4] = {0.f, 0.f, 0.f, 0.f};
#pragma unroll
        for (int j = 0; j < 4; ++j) {
            float mnew = fmaxf(mj[j], pmax[j]);
            float alpha = (mnew <= -1e29f) ? 1.0f : __expf(mj[j] - mnew);
            mj[j] = mnew;
            lj[j] *= alpha;
#pragma unroll
            for (int nd = 0; nd < 4; ++nd) oacc[nd][j] *= alpha;
        }
#pragma unroll
        for (int n = 0; n < 4; ++n) {
#pragma unroll
            for (int j = 0; j < 4; ++j) {
                float sv = s[n][j];
                float p = (sv <= -1e29f) ? 0.f : __expf(sv - mj[j]);
                tl[j] += p;
                Ps[wv][(fq * 4 + j) * 72 + n * 16 + fr] = f2bf(p);
            }
        }
#pragma unroll
        for (int off = 1; off < 16; off <<= 1)
#pragma unroll
            for (int j = 0; j < 4; ++j)
                tl[j] += __shfl_xor(tl[j], off);
#pragma unroll
        for (int j = 0; j < 4; ++j) lj[j] += tl[j];

        // ---- PV: A = P (LDS bounce does the transpose), B = Vt ----
        bf16x8 pa0 = *(const bf16x8*)&Ps[wv][fr * 72 + fq * 8];
        bf16x8 pa1 = *(const bf16x8*)&Ps[wv][fr * 72 + 32 + fq * 8];
#pragma unroll
        for (int nd = 0; nd < 4; ++nd) {
            bf16x8 vb0 = *(const bf16x8*)&Vt[(nd * 16 + fr) * 72 + fq * 8];
            bf16x8 vb1 = *(const bf16x8*)&Vt[(nd * 16 + fr) * 72 + 32 + fq * 8];
            oacc[nd] = __builtin_amdgcn_mfma_f32_16x16x32_bf16(pa0, vb0, oacc[nd], 0, 0, 0);
            oacc[nd] = __builtin_amdgcn_mfma_f32_16x16x32_bf16(pa1, vb1, oacc[nd], 0, 0, 0);
        }
    }

    // ---- epilogue ----
#pragma unroll
    for (int nd = 0; nd < 4; ++nd) {
#pragma unroll
        for (int j = 0; j < 4; ++j) {
            const int qi = q0 + wv * 16 + fq * 4 + j;
            out[(size_t)(b * TT + qi) * CC + h * DD + nd * 16 + fr] =
                f2bf(oacc[nd][j] / lj[j]);
        }
    }
}

// ---------------------------------------------------------------------------
extern "C" void kernel_launch(void* const* d_in, const int* in_sizes, int n_in,
                              void* d_out, int out_size, void* d_ws, size_t ws_size,
                              hipStream_t stream) {
    const float* x     = (const float*)d_in[0];
    const float* w_qkv = (const float*)d_in[1];
    const float* w_out = (const float*)d_in[2];
    const float* b_out = (const float*)d_in[3];
    float* out = (float*)d_out;

    ushort_t* qkv_b  = (ushort_t*)d_ws;
    ushort_t* attn_b = qkv_b  + (size_t)MROWS * NQKV;
    ushort_t* xb     = attn_b + (size_t)MROWS * CC;
    ushort_t* wqb    = xb     + (size_t)MROWS * CC;
    ushort_t* wob    = wqb    + (size_t)NQKV * CC;

    f32_to_bf16<<<(MROWS * CC) / 1024, 256, 0, stream>>>(x, xb);
    f32_to_bf16<<<(NQKV * CC) / 1024, 256, 0, stream>>>(w_qkv, wqb);
    f32_to_bf16<<<(CC * CC) / 1024, 256, 0, stream>>>(w_out, wob);

    gemm_nt_mfma<false, true><<<dim3(NQKV / 128, MROWS / 128), 256, 0, stream>>>(
        xb, wqb, nullptr, qkv_b, MROWS, NQKV, CC);

    rope_kernel<<<(BB * TT * HH * 32) / 256, 256, 0, stream>>>(qkv_b);

    attn_mfma<<<BB * HH * (TT / 64), 256, 0, stream>>>(qkv_b, attn_b);

    gemm_nt_mfma<true, false><<<dim3(CC / 128, MROWS / 128), 256, 0, stream>>>(
        attn_b, wob, b_out, out, MROWS, CC, CC);
}